// Round 8
// baseline (3035.401 us; speedup 1.0000x reference)
//
#include <hip/hip_runtime.h>
#include <math.h>

#define Bn 8
#define Nn 8192
#define Dn 64
#define Sn 2048
#define NS 32
#define NCONS 120
#define LAG 8
#define PSTR 64   // prog padding: one 256B line per batch counter

typedef float f2 __attribute__((ext_vector_type(2)));
typedef unsigned long long u64;

// DPP helper: returns permuted src (untouched lanes keep own value).
#define DPP_STEP(v, ctrl, rmask)                                               \
    __builtin_amdgcn_update_dpp((v), (v), (ctrl), (rmask), 0xf, false)

// Device-scope (AGENT) relaxed atomics -> coherent point (cross-XCD safe).
#define ATOMIC_ST(p, v) __hip_atomic_store((p), (v), __ATOMIC_RELAXED, __HIP_MEMORY_SCOPE_AGENT)
#define ATOMIC_LD(p)    __hip_atomic_load((p), __ATOMIC_RELAXED, __HIP_MEMORY_SCOPE_AGENT)

// LDS-only barrier: drain LDS, sync, pin scheduling; do NOT drain vmem
// (producer's publish stores stay in flight -> no per-iter store-latency stall).
#define LDS_BARRIER()                                                          \
    do {                                                                       \
        asm volatile("s_waitcnt lgkmcnt(0)" ::: "memory");                     \
        __builtin_amdgcn_s_barrier();                                          \
        __builtin_amdgcn_sched_barrier(0);                                     \
    } while (0)

// ---------------------------------------------------------------------------
// Single fused kernel, 512 threads/block, 128 blocks (<=256 CUs, ~130KB LDS
// -> 1 block/CU -> all co-resident, spins cannot deadlock).
//  blocks 0..7   : FPS producer for batch b (8 waves, 16 pts/thread).
//                  Tail: DPP wave-max -> u64 key -> LDS -> 7 u64-max merge ->
//                  broadcast lxyz[winner] read. One barrier per iteration.
//  blocks 8..127 : consumers. Startup: transpose points -> ptT [B,N,D] (sc1
//                  stores), block 8 folds BN -> wb, done-handshake. Main:
//                  wave w = batch w; lanes 0-31 sample t1, lanes 32-63
//                  sample t2 = t1+NCONS; ballq + MLP + maxpool.
// prog[b*PSTR] = t-LAG+1 published at iter t (~6us lag >> store latency) so
// consumers never observe a published-but-incomplete coordinate.
// ---------------------------------------------------------------------------
__global__ __launch_bounds__(512, 2)
void fused_kernel(const float* __restrict__ xyz, const float* __restrict__ pts,
                  float* __restrict__ wb, float* __restrict__ newxyz_f,
                  float* __restrict__ outp, int* __restrict__ prog,
                  int* __restrict__ done, float* __restrict__ ptT,
                  const float* __restrict__ w0g, const float* __restrict__ w1g,
                  const float* __restrict__ w2g,
                  const float* __restrict__ g0, const float* __restrict__ b0,
                  const float* __restrict__ m0, const float* __restrict__ v0,
                  const float* __restrict__ g1, const float* __restrict__ b1,
                  const float* __restrict__ m1, const float* __restrict__ v1,
                  const float* __restrict__ g2, const float* __restrict__ b2,
                  const float* __restrict__ m2, const float* __restrict__ v2)
{
#pragma clang fp contract(off)
    __shared__ float4 lxyz[Nn];                 // 128 KB (fps) / transpose tile alias
    __shared__ u64    ckey[2][8];
    __shared__ int    lidx[8][2][NS];           // 2 KB (consumer)
    const int tid = threadIdx.x;
    const int lane = tid & 63;
    const int wv = tid >> 6;                    // wave 0..7
    int* newxyz_i = (int*)newxyz_f;

    if (blockIdx.x < Bn) {
        // ===================== producer: FPS =====================
        const int b = blockIdx.x;
        const float* xb = xyz + (size_t)b * 3 * Nn;
        f2 px[8], py[8], pz[8], pd[8];
        const int base = tid * 16;
#pragma unroll
        for (int q = 0; q < 4; ++q) {
            float4 vx = *(const float4*)(xb + base + 4 * q);
            float4 vy = *(const float4*)(xb + Nn + base + 4 * q);
            float4 vz = *(const float4*)(xb + 2 * Nn + base + 4 * q);
            px[2 * q]     = (f2){vx.x, vx.y};  px[2 * q + 1] = (f2){vx.z, vx.w};
            py[2 * q]     = (f2){vy.x, vy.y};  py[2 * q + 1] = (f2){vy.z, vy.w};
            pz[2 * q]     = (f2){vz.x, vz.y};  pz[2 * q + 1] = (f2){vz.z, vz.w};
            pd[2 * q]     = (f2){1e10f, 1e10f};
            pd[2 * q + 1] = (f2){1e10f, 1e10f};
            lxyz[base + 4 * q + 0] = make_float4(vx.x, vy.x, vz.x, 0.f);
            lxyz[base + 4 * q + 1] = make_float4(vx.y, vy.y, vz.y, 0.f);
            lxyz[base + 4 * q + 2] = make_float4(vx.z, vy.z, vz.z, 0.f);
            lxyz[base + 4 * q + 3] = make_float4(vx.w, vy.w, vz.w, 0.f);
        }
        float cx = xb[0], cy = xb[Nn], cz = xb[2 * Nn];
        const size_t nb0 = (size_t)b * 3 * Sn;
        if (tid == 0) {
            ATOMIC_ST(newxyz_i + nb0,          __float_as_int(cx));
            ATOMIC_ST(newxyz_i + nb0 + Sn,     __float_as_int(cy));
            ATOMIC_ST(newxyz_i + nb0 + 2 * Sn, __float_as_int(cz));
        }
        __syncthreads();

        for (int t = 1; t < Sn; ++t) {
            f2 c0 = {cx, cx}, c1 = {cy, cy}, c2 = {cz, cz};
            // two parallel argmax chains (elems 0-7 / 8-15); merge prefers
            // chain A on ties -> first-occurrence (A's elems have smaller idx)
            float bA = -1.0f, bB = -1.0f; int gA = 0, gB = 0;
#pragma unroll
            for (int i = 0; i < 4; ++i) {
                f2 dx = px[i] - c0, dy = py[i] - c1, dz = pz[i] - c2;
                f2 s0 = dx * dx, s1 = dy * dy, s2 = dz * dz;
                f2 d = (s0 + s1) + s2;         // ((dx2+dy2)+dz2) per component
                f2 nd; nd.x = fminf(pd[i].x, d.x); nd.y = fminf(pd[i].y, d.y);
                pd[i] = nd;
                if (nd.x > bA) { bA = nd.x; gA = base + 2 * i; }      // strict >
                if (nd.y > bA) { bA = nd.y; gA = base + 2 * i + 1; }  // => first
            }
#pragma unroll
            for (int i = 4; i < 8; ++i) {
                f2 dx = px[i] - c0, dy = py[i] - c1, dz = pz[i] - c2;
                f2 s0 = dx * dx, s1 = dy * dy, s2 = dz * dz;
                f2 d = (s0 + s1) + s2;
                f2 nd; nd.x = fminf(pd[i].x, d.x); nd.y = fminf(pd[i].y, d.y);
                pd[i] = nd;
                if (nd.x > bB) { bB = nd.x; gB = base + 2 * i; }
                if (nd.y > bB) { bB = nd.y; gB = base + 2 * i + 1; }
            }
            float best; int gi;
            if (bB > bA) { best = bB; gi = gB; } else { best = bA; gi = gA; }
            // wave value-max via DPP (VALU pipe)
            int vb = __float_as_int(best);     // dists >= 0: bit-monotone
            { int s_;
              s_ = DPP_STEP(vb, 0x111, 0xf); vb = __float_as_int(fmaxf(__int_as_float(vb), __int_as_float(s_)));
              s_ = DPP_STEP(vb, 0x112, 0xf); vb = __float_as_int(fmaxf(__int_as_float(vb), __int_as_float(s_)));
              s_ = DPP_STEP(vb, 0x114, 0xf); vb = __float_as_int(fmaxf(__int_as_float(vb), __int_as_float(s_)));
              s_ = DPP_STEP(vb, 0x118, 0xf); vb = __float_as_int(fmaxf(__int_as_float(vb), __int_as_float(s_)));
              s_ = DPP_STEP(vb, 0x142, 0xa); vb = __float_as_int(fmaxf(__int_as_float(vb), __int_as_float(s_)));
              s_ = DPP_STEP(vb, 0x143, 0xc); vb = __float_as_int(fmaxf(__int_as_float(vb), __int_as_float(s_)));
            }
            const int smax = __builtin_amdgcn_readlane(vb, 63);
            const float wmaxf = __int_as_float(smax);
            u64 m = __ballot(best == wmaxf);
            int fl = (int)__ffsll((long long)m) - 1;     // lowest lane = smallest idx
            int gw_ = __builtin_amdgcn_readlane(gi, fl);
            if (lane == 0)
                ckey[t & 1][wv] = ((u64)(unsigned)smax << 32) | (unsigned)(8191 - gw_);
            LDS_BARRIER();                               // LDS-only drain (no vmcnt)
            // keys-only merge: ties impossible (idx embedded); any order ok
            u64 k0 = ckey[t & 1][0], k1 = ckey[t & 1][1];
            u64 k2 = ckey[t & 1][2], k3 = ckey[t & 1][3];
            u64 k4 = ckey[t & 1][4], k5 = ckey[t & 1][5];
            u64 k6 = ckey[t & 1][6], k7 = ckey[t & 1][7];
            u64 a0 = (k1 > k0) ? k1 : k0;
            u64 a1 = (k3 > k2) ? k3 : k2;
            u64 a2 = (k5 > k4) ? k5 : k4;
            u64 a3 = (k7 > k6) ? k7 : k6;
            u64 b0_ = (a1 > a0) ? a1 : a0;
            u64 b1_ = (a3 > a2) ? a3 : a2;
            u64 kw = (b1_ > b0_) ? b1_ : b0_;
            const int win = 8191 - (int)(kw & 0x3FFFu);
            float4 cen = lxyz[win];                      // broadcast ds_read_b128
            cx = cen.x; cy = cen.y; cz = cen.z;
            if (tid == 0) {
                ATOMIC_ST(prog + b * PSTR, t - (LAG - 1));   // lagged publish
                ATOMIC_ST(newxyz_i + nb0 + t,          __float_as_int(cx));
                ATOMIC_ST(newxyz_i + nb0 + Sn + t,     __float_as_int(cy));
                ATOMIC_ST(newxyz_i + nb0 + 2 * Sn + t, __float_as_int(cz));
            }
        }
        if (tid == 0) {
            asm volatile("s_waitcnt vmcnt(0)" ::: "memory");  // drain coord stores
            ATOMIC_ST(prog + b * PSTR, Sn);
        }
    } else {
        // ===================== consumer =====================
        const int cid = blockIdx.x - Bn;        // 0..NCONS-1
        const int w = wv;                       // wave = batch
        const int k = lane & 31;
        const int half = lane >> 5;
        // ---- startup phase: transpose (+ BN fold by block cid==0) ----
        {
            float (*tile)[65] = (float (*)[65])lxyz;
            for (int tb = cid; tb < Bn * (Nn / 64); tb += NCONS) {
                const int b = tb >> 7;
                const int j0 = (tb & 127) << 6;
                const float* src = pts + (size_t)b * Dn * Nn;
#pragma unroll
                for (int i = 0; i < 8; ++i) {
                    int d = w * 8 + i;
                    tile[d][lane] = src[(size_t)d * Nn + j0 + lane];
                }
                __syncthreads();
                float* dst = ptT + ((size_t)b * Nn + j0) * Dn;
#pragma unroll
                for (int i = 0; i < 8; ++i) {
                    int jj = w * 8 + i;
                    ATOMIC_ST((int*)(dst + (size_t)jj * Dn + lane),
                              __float_as_int(tile[lane][jj]));
                }
                __syncthreads();
            }
            if (cid == 0) {                     // fold BN into weights -> wb
                for (int u = tid; u < 8192; u += 512) {
                    if (u < 4288) { int c = u / 67; float sc = g0[c] / sqrtf(v0[c] + 1e-5f);
                                    ATOMIC_ST((int*)(wb + u), __float_as_int(w0g[u] * sc)); }
                    if (u < 64)   { float sc = g0[u] / sqrtf(v0[u] + 1e-5f);
                                    ATOMIC_ST((int*)(wb + 4288 + u), __float_as_int(b0[u] - m0[u] * sc)); }
                    if (u < 4096) { int c = u / 64; float sc = g1[c] / sqrtf(v1[c] + 1e-5f);
                                    ATOMIC_ST((int*)(wb + 4352 + u), __float_as_int(w1g[u] * sc)); }
                    if (u < 64)   { float sc = g1[u] / sqrtf(v1[u] + 1e-5f);
                                    ATOMIC_ST((int*)(wb + 8448 + u), __float_as_int(b1[u] - m1[u] * sc)); }
                    if (u < 8192) { int c = u / 64; float sc = g2[c] / sqrtf(v2[c] + 1e-5f);
                                    ATOMIC_ST((int*)(wb + 8512 + u), __float_as_int(w2g[u] * sc)); }
                    if (u < 128)  { float sc = g2[u] / sqrtf(v2[u] + 1e-5f);
                                    ATOMIC_ST((int*)(wb + 16704 + u), __float_as_int(b2[u] - m2[u] * sc)); }
                }
            }
            asm volatile("s_waitcnt vmcnt(0)" ::: "memory");  // every thread drains
            __syncthreads();
            if (tid == 0) {
                __hip_atomic_fetch_add(done, 1, __ATOMIC_RELAXED, __HIP_MEMORY_SCOPE_AGENT);
                while (ATOMIC_LD(done) != NCONS) __builtin_amdgcn_s_sleep(32);
            }
            __syncthreads();
        }
        // ---- main loop: lanes 0-31 -> sample t1, lanes 32-63 -> t2 ----
        const float R2 = (float)(0.4 * 0.4);    // 0.15999999642f, matches numpy
        for (int t1 = cid; t1 < Sn; t1 += 2 * NCONS) {
            const int t2 = t1 + NCONS;
            const bool two = (t2 < Sn);
            const int tmax = two ? t2 : t1;
            if (tid < Bn) {
                while (ATOMIC_LD(prog + tid * PSTR) < tmax + 1) __builtin_amdgcn_s_sleep(32);
            }
            __syncthreads();
            const int myt = (half && two) ? t2 : t1;
            const size_t nb = (size_t)w * 3 * Sn;
            const float cxm = __int_as_float(ATOMIC_LD(newxyz_i + nb + myt));
            const float cym = __int_as_float(ATOMIC_LD(newxyz_i + nb + Sn + myt));
            const float czm = __int_as_float(ATOMIC_LD(newxyz_i + nb + 2 * Sn + myt));
            // ---- ball query: h=0 for t1 (bcast lane 0), h=1 for t2 (lane 32) ----
            const float* xb = xyz + (size_t)w * 3 * Nn;
#pragma unroll
            for (int h = 0; h < 2; ++h) {
                const float cx = __shfl(cxm, h * 32);
                const float cy = __shfl(cym, h * 32);
                const float cz = __shfl(czm, h * 32);
                int cnt = 0, first = -1;
                for (int bs2 = 0; bs2 < Nn && cnt < NS; bs2 += 64) {
                    int jj = bs2 + lane;
                    float dx = cx - xb[jj];
                    float dy = cy - xb[Nn + jj];
                    float dz = cz - xb[2 * Nn + jj];
                    float d = (dx * dx + dy * dy) + dz * dz;
                    bool hit = d <= R2;
                    u64 m = __ballot(hit);
                    if (hit) {
                        int pos = cnt + __popcll(m & ((1ull << lane) - 1ull));
                        if (pos < NS) lidx[w][h][pos] = jj;
                    }
                    if (first < 0 && m != 0ull) first = bs2 + (int)__ffsll((long long)m) - 1;
                    cnt += (int)__popcll(m);
                }
                for (int p = cnt + lane; p < NS; p += 64) lidx[w][h][p] = first;
            }
            // ---- MLP: each lane one (sample,k) ----
            const int j = lidx[w][(half && two) ? 1 : 0][k];
            const float x0 = xb[j]          - cxm;
            const float x1 = xb[Nn + j]     - cym;
            const float x2 = xb[2 * Nn + j] - czm;
            const float* pb = ptT + ((size_t)w * Nn + j) * Dn;
            float xf[64];
#pragma unroll
            for (int d0 = 0; d0 < 64; d0 += 4) {
                float4 v = *(const float4*)(pb + d0);
                xf[d0] = v.x; xf[d0 + 1] = v.y; xf[d0 + 2] = v.z; xf[d0 + 3] = v.w;
            }
            const float* w0  = wb;
            const float* bb0 = wb + 64 * 67;
            float h0[64];
#pragma unroll 2
            for (int c = 0; c < 64; ++c) {
                const float* wr = w0 + c * 67;
                float a0 = fmaf(wr[0], x0, bb0[c]);
                float a1 = wr[1] * x1;
                float a2 = wr[2] * x2;
                float a3 = 0.0f;
#pragma unroll
                for (int d = 0; d < 64; d += 4) {
                    a0 = fmaf(wr[3 + d], xf[d],     a0);
                    a1 = fmaf(wr[4 + d], xf[d + 1], a1);
                    a2 = fmaf(wr[5 + d], xf[d + 2], a2);
                    a3 = fmaf(wr[6 + d], xf[d + 3], a3);
                }
                h0[c] = fmaxf((a0 + a1) + (a2 + a3), 0.0f);
            }
            const float* w1  = wb + 4352;
            const float* bb1 = wb + 8448;
            float h1[64];
#pragma unroll 2
            for (int c = 0; c < 64; ++c) {
                const float* wr = w1 + c * 64;
                float a0 = bb1[c], a1 = 0.f, a2 = 0.f, a3 = 0.f;
#pragma unroll
                for (int d = 0; d < 64; d += 4) {
                    a0 = fmaf(wr[d],     h0[d],     a0);
                    a1 = fmaf(wr[d + 1], h0[d + 1], a1);
                    a2 = fmaf(wr[d + 2], h0[d + 2], a2);
                    a3 = fmaf(wr[d + 3], h0[d + 3], a3);
                }
                h1[c] = fmaxf((a0 + a1) + (a2 + a3), 0.0f);
            }
            const float* w2  = wb + 8512;
            const float* bb2 = wb + 16704;
            float* ob = outp + ((size_t)w * 128) * Sn + myt;
            const bool wr_ok = (k == 0) && (two || !half);
#pragma unroll 2
            for (int c = 0; c < 128; ++c) {
                const float* wr = w2 + c * 64;
                float a0 = bb2[c], a1 = 0.f, a2 = 0.f, a3 = 0.f;
#pragma unroll
                for (int d = 0; d < 64; d += 4) {
                    a0 = fmaf(wr[d],     h1[d],     a0);
                    a1 = fmaf(wr[d + 1], h1[d + 1], a1);
                    a2 = fmaf(wr[d + 2], h1[d + 2], a2);
                    a3 = fmaf(wr[d + 3], h1[d + 3], a3);
                }
                float acc = fmaxf((a0 + a1) + (a2 + a3), 0.0f);
#pragma unroll
                for (int off = 1; off < 32; off <<= 1) acc = fmaxf(acc, __shfl_xor(acc, off));
                if (wr_ok) ob[(size_t)c * Sn] = acc;
            }
        }
    }
}

extern "C" void kernel_launch(void* const* d_in, const int* in_sizes, int n_in,
                              void* d_out, int out_size, void* d_ws, size_t ws_size,
                              hipStream_t stream)
{
    const float* xyz    = (const float*)d_in[0];
    const float* points = (const float*)d_in[1];
    const float* w0 = (const float*)d_in[2];
    const float* w1 = (const float*)d_in[3];
    const float* w2 = (const float*)d_in[4];
    const float* g0 = (const float*)d_in[5];
    const float* b0 = (const float*)d_in[6];
    const float* m0 = (const float*)d_in[7];
    const float* v0 = (const float*)d_in[8];
    const float* g1 = (const float*)d_in[9];
    const float* b1 = (const float*)d_in[10];
    const float* m1 = (const float*)d_in[11];
    const float* v1 = (const float*)d_in[12];
    const float* g2 = (const float*)d_in[13];
    const float* b2 = (const float*)d_in[14];
    const float* m2 = (const float*)d_in[15];
    const float* v2 = (const float*)d_in[16];

    float* out  = (float*)d_out;                       // new_xyz [8,3,2048] then new_points [8,128,2048]
    float* wb   = (float*)d_ws;                        // 16832 floats of folded weights
    int*   prog = (int*)((char*)d_ws + 128 * 1024);    // padded per-batch progress (8 x 256B)
    int*   done = (int*)((char*)d_ws + 128 * 1024 + 2048);  // startup handshake counter
    float* ptT  = (float*)((char*)d_ws + 192 * 1024);  // transposed points [B,N,D] = 16.78 MB

    hipMemsetAsync((char*)d_ws + 128 * 1024, 0, 4096, stream);  // zero prog + done
    fused_kernel<<<Bn + NCONS, 512, 0, stream>>>(
        xyz, points, wb, out, out + Bn * 3 * Sn, prog, done, ptT,
        w0, w1, w2, g0, b0, m0, v0, g1, b1, m1, v1, g2, b2, m2, v2);
}